// Round 3
// baseline (930.651 us; speedup 1.0000x reference)
//
#include <hip/hip_runtime.h>
#include <float.h>
#include <limits.h>

// RankLoss round 5.
// Round-4 post-mortem: DPP + persistent cooperative regressed 3.4x (VALU
// cycles unchanged but wall time exploded -> serial DPP hazard chains +
// loss of block-turnover memory feeding). Reverted both.
// Key measurement kept from round 4: residual (non-kernel) time scales with
// launch count (~65us/launch: 3 launches -> 195us residual, 1 launch -> 59us).
// So round 5 = round-3 stats code (proven 118us, shfl-based, one unit per
// wave, non-persistent) + last-block-done finisher (threadfence + atomic
// counter) doing combine+reduce in the same launch. One tiny memset resets
// the counter each call (workspace may be re-poisoned between runs).

constexpr int B      = 32768;
constexpr int C_ENT  = 1000;   // 250 float4
constexpr int C_REL  = 500;    // 125 float4
constexpr int NUNITS = 3 * B / 2;   // 49152 wave-units: (row-pair, matrix)

// ---------------- per-(row-pair, matrix) wave stats (round-3 proven code) ----------------

// lane-local top-2 over NK float4s.
// merge: top1' = max(h1,h2); top2' = max(l1, l2, min(h1,h2))  -> v_max3
template<int NK>
__device__ inline void lane_top2(const float4* v, float& m1, float& m2) {
  float hi[2 * NK], lo[2 * NK];
#pragma unroll
  for (int k = 0; k < NK; ++k) {
    hi[2 * k]     = fmaxf(v[k].x, v[k].y);
    lo[2 * k]     = fminf(v[k].x, v[k].y);
    hi[2 * k + 1] = fmaxf(v[k].z, v[k].w);
    lo[2 * k + 1] = fminf(v[k].z, v[k].w);
  }
#pragma unroll
  for (int half = NK; half >= 1; half >>= 1) {
#pragma unroll
    for (int i = 0; i < half; ++i) {
      const float ha = hi[i], hb = hi[i + half];
      const float la = lo[i], lb = lo[i + half];
      hi[i] = fmaxf(ha, hb);
      lo[i] = fmaxf(fmaxf(la, lb), fminf(ha, hb));
    }
  }
  m1 = hi[0];
  m2 = lo[0];
}

// lane-local exp-sum vs global max m1, min index among elements == m1.
// sentinel elements are -FLT_MAX: exp underflows to 0, eq never fires.
template<int NK>
__device__ inline void lane_z_idx(const float4* v, int lane, float m1, float& z, int& idx) {
  float zp[NK];
  idx = INT_MAX;
#pragma unroll
  for (int k = 0; k < NK; ++k) {
    const int base = 4 * (lane + 64 * k);
    const float a0 = v[k].x, a1 = v[k].y, a2 = v[k].z, a3 = v[k].w;
    zp[k] = (__expf(a0 - m1) + __expf(a1 - m1)) + (__expf(a2 - m1) + __expf(a3 - m1));
    const int i01 = min(a0 == m1 ? base     : INT_MAX, a1 == m1 ? base + 1 : INT_MAX);
    const int i23 = min(a2 == m1 ? base + 2 : INT_MAX, a3 == m1 ? base + 3 : INT_MAX);
    idx = min(idx, min(i01, i23));
  }
  if constexpr (NK == 4) z = (zp[0] + zp[1]) + (zp[2] + zp[3]);
  else                   z = zp[0] + zp[1];
}

template<int NK, int C4>
__device__ inline void wave_stats2(const float* __restrict__ rowA,
                                   const float* __restrict__ rowB,
                                   int lane, int tA, int tB,
                                   float4* __restrict__ outp) {
  const float4* a4 = (const float4*)rowA;
  const float4* b4 = (const float4*)rowB;
  float4 va[NK], vb[NK];
#pragma unroll
  for (int k = 0; k < NK - 1; ++k) {   // full chunks: provably in bounds
    va[k] = a4[lane + 64 * k];
    vb[k] = b4[lane + 64 * k];
  }
  {  // tail chunk: clamp address (rows end on an allocation boundary), mask lanes
    const int  i  = lane + 64 * (NK - 1);
    const bool ok = (i < C4);
    const int  ic = ok ? i : (C4 - 1);
    float4 ta = a4[ic], tb = b4[ic];
    ta.x = ok ? ta.x : -FLT_MAX;  ta.y = ok ? ta.y : -FLT_MAX;
    ta.z = ok ? ta.z : -FLT_MAX;  ta.w = ok ? ta.w : -FLT_MAX;
    tb.x = ok ? tb.x : -FLT_MAX;  tb.y = ok ? tb.y : -FLT_MAX;
    tb.z = ok ? tb.z : -FLT_MAX;  tb.w = ok ? tb.w : -FLT_MAX;
    va[NK - 1] = ta;
    vb[NK - 1] = tb;
  }
  const float xa = rowA[tA];   // broadcast loads, issued with the vectors
  const float xb = rowB[tB];

  // ---- lane-local top-2, then joint (m1,m2) butterfly ----
  float m1a, m2a, m1b, m2b;
  lane_top2<NK>(va, m1a, m2a);
  lane_top2<NK>(vb, m1b, m2b);

#pragma unroll
  for (int off = 32; off; off >>= 1) {
    const float p1a = __shfl_xor(m1a, off), p2a = __shfl_xor(m2a, off);
    const float p1b = __shfl_xor(m1b, off), p2b = __shfl_xor(m2b, off);
    m2a = fmaxf(fmaxf(m2a, p2a), fminf(m1a, p1a));
    m1a = fmaxf(m1a, p1a);
    m2b = fmaxf(fmaxf(m2b, p2b), fminf(m1b, p1b));
    m1b = fmaxf(m1b, p1b);
  }

  // ---- exp pass + argmax (exact ==, fmax/shuffle preserve bits) ----
  float za, zb;
  int   ia, ib;
  lane_z_idx<NK>(va, lane, m1a, za, ia);
  lane_z_idx<NK>(vb, lane, m1b, zb, ib);

#pragma unroll
  for (int off = 32; off; off >>= 1) {
    za += __shfl_xor(za, off);
    zb += __shfl_xor(zb, off);
    ia  = min(ia, __shfl_xor(ia, off));
    ib  = min(ib, __shfl_xor(ib, off));
  }

  if (lane == 0) {
    const float iZa = 1.0f / za;
    const float iZb = 1.0f / zb;
    outp[0] = make_float4(iZa, __expf(m2a - m1a) * iZa, __expf(xa - m1a) * iZa,
                          __int_as_float(ia));
    outp[1] = make_float4(iZb, __expf(m2b - m1b) * iZb, __expf(xb - m1b) * iZb,
                          __int_as_float(ib));
  }
}

__device__ inline void do_unit(int gw,
    const float* __restrict__ s, const float* __restrict__ r, const float* __restrict__ o,
    const int* __restrict__ st, const int* __restrict__ rt, const int* __restrict__ ot,
    float4* __restrict__ stat4, int lane) {
  const int m   = gw >> 14;          // 16384 row-pairs per matrix
  const int row = (gw & 16383) * 2;
  if (m == 0)
    wave_stats2<4, C_ENT / 4>(s + (size_t)row * C_ENT, s + (size_t)(row + 1) * C_ENT,
                              lane, st[row], st[row + 1], stat4 + row);
  else if (m == 1)
    wave_stats2<4, C_ENT / 4>(o + (size_t)row * C_ENT, o + (size_t)(row + 1) * C_ENT,
                              lane, ot[row], ot[row + 1], stat4 + B + row);
  else
    wave_stats2<2, C_REL / 4>(r + (size_t)row * C_REL, r + (size_t)(row + 1) * C_REL,
                              lane, rt[row], rt[row + 1], stat4 + 2 * B + row);
}

__device__ inline float row_loss(const float4* __restrict__ stat4, int row,
                                 int ts, int tr, int to) {
  const float4 S = stat4[row];           // m=0
  const float4 O = stat4[B + row];       // m=1
  const float4 R = stat4[2 * B + row];   // m=2
  const float gt   = S.z * R.z * O.z;
  const float top1 = S.x * R.x * O.x;
  // second-smallest of the 8 top2-products = min of the three one-swap products
  const float c1 = S.x * R.y * O.y;
  const float c2 = S.y * R.x * O.y;
  const float c3 = S.y * R.y * O.x;
  const float second = fminf(c1, fminf(c2, c3));
  const bool cond = (__float_as_int(S.w) == ts) &&
                    (__float_as_int(R.w) == tr) &&
                    (__float_as_int(O.w) == to);
  const float pre = cond ? second : top1;
  return fmaxf(1.0f - gt + pre, 0.0f);
}

// ---------------- single-launch kernel: stats + last-block finisher ----------------

__global__ __launch_bounds__(256) void stats_finish_kernel(
    const float* __restrict__ s, const float* __restrict__ r, const float* __restrict__ o,
    const int* __restrict__ st, const int* __restrict__ rt, const int* __restrict__ ot,
    float4* __restrict__ stat4, unsigned* __restrict__ counter,
    float* __restrict__ out) {
  const int wid  = threadIdx.x >> 6;
  const int lane = threadIdx.x & 63;
  do_unit(blockIdx.x * 4 + wid, s, r, o, st, rt, ot, stat4, lane);

  // ---- elect the last-finishing block (rocPRIM device-reduce idiom) ----
  __shared__ unsigned isLast;
  __syncthreads();                 // all 4 waves' stat4 stores issued & drained
  if (threadIdx.x == 0) {
    __threadfence();               // release: publish stat4 device-wide (cross-XCD)
    isLast = (atomicAdd(counter, 1u) == (unsigned)(gridDim.x - 1));
  }
  __syncthreads();
  if (!isLast) return;

  // ---- finisher: combine + reduce for all rows ----
  __threadfence();                 // acquire: observe all blocks' stat4 writes
  float sum = 0.f;
  for (int row = threadIdx.x; row < B; row += 256)
    sum += row_loss(stat4, row, st[row], rt[row], ot[row]);
#pragma unroll
  for (int off = 32; off; off >>= 1) sum += __shfl_xor(sum, off);
  __shared__ float lds[4];
  if (lane == 0) lds[wid] = sum;
  __syncthreads();
  if (threadIdx.x == 0)
    out[0] = ((lds[0] + lds[1]) + (lds[2] + lds[3])) * (1.0f / (float)B);
}

// ---------------- fallback: one wave per row, atomic accumulate (tiny ws) ----------------

__device__ inline void combine_stats(float& m1, int& i1, float& m2, float& Z,
                                     float bm1, int bi1, float bm2, float bZ) {
  bool bwin = (bm1 > m1) || (bm1 == m1 && bi1 < i1);
  float wm1 = bwin ? bm1 : m1;
  int   wi1 = bwin ? bi1 : i1;
  float wm2 = bwin ? bm2 : m2;
  float lm1 = bwin ? m1  : bm1;
  float wZ  = bwin ? bZ  : Z;
  float lZ  = bwin ? Z   : bZ;
  m1 = wm1; i1 = wi1;
  m2 = fmaxf(wm2, lm1);
  Z  = wZ + lZ * __expf(lm1 - wm1);
}

template<int NK, int C4>
__device__ inline void row_stats(const float* __restrict__ row, int lane, int target,
                                 float& p_top1, float& p_top2, int& amax, float& p_tgt) {
  const float4* row4 = (const float4*)row;
  float4 v[NK];
#pragma unroll
  for (int k = 0; k < NK; ++k) {
    int idx = lane + 64 * k;
    v[k] = (idx < C4) ? row4[idx] : make_float4(-FLT_MAX, -FLT_MAX, -FLT_MAX, -FLT_MAX);
  }
  float m1 = -FLT_MAX, m2 = -FLT_MAX;
  int   i1 = 0x7fffffff;
#pragma unroll
  for (int k = 0; k < NK; ++k) {
    int base = 4 * (lane + 64 * k);
    float a0 = v[k].x, a1 = v[k].y, a2 = v[k].z, a3 = v[k].w;
    if (a0 > m1) { m2 = m1; m1 = a0; i1 = base;     } else if (a0 > m2) m2 = a0;
    if (a1 > m1) { m2 = m1; m1 = a1; i1 = base + 1; } else if (a1 > m2) m2 = a1;
    if (a2 > m1) { m2 = m1; m1 = a2; i1 = base + 2; } else if (a2 > m2) m2 = a2;
    if (a3 > m1) { m2 = m1; m1 = a3; i1 = base + 3; } else if (a3 > m2) m2 = a3;
  }
  float Z = 0.f;
#pragma unroll
  for (int k = 0; k < NK; ++k) {
    Z += __expf(v[k].x - m1); Z += __expf(v[k].y - m1);
    Z += __expf(v[k].z - m1); Z += __expf(v[k].w - m1);
  }
#pragma unroll
  for (int off = 32; off > 0; off >>= 1) {
    float bm1 = __shfl_xor(m1, off);
    int   bi1 = __shfl_xor(i1, off);
    float bm2 = __shfl_xor(m2, off);
    float bZ  = __shfl_xor(Z,  off);
    combine_stats(m1, i1, m2, Z, bm1, bi1, bm2, bZ);
  }
  float invZ = 1.0f / Z;
  float xt   = row[target];
  p_top1 = invZ;
  p_top2 = __expf(m2 - m1) * invZ;
  p_tgt  = __expf(xt - m1) * invZ;
  amax   = i1;
}

__global__ __launch_bounds__(256) void rank_loss_kernel(
    const float* __restrict__ s, const float* __restrict__ r, const float* __restrict__ o,
    const int* __restrict__ st, const int* __restrict__ rt, const int* __restrict__ ot,
    float* __restrict__ out) {
  const int wid  = threadIdx.x >> 6;
  const int lane = threadIdx.x & 63;
  const int row  = blockIdx.x * 4 + wid;

  const int tS = st[row], tR = rt[row], tO = ot[row];
  float sp0, sp1, spt; int sa;
  float rp0, rp1, rpt; int ra;
  float op0, op1, opt; int oa;
  row_stats<4, C_ENT / 4>(s + (size_t)row * C_ENT, lane, tS, sp0, sp1, sa, spt);
  row_stats<2, C_REL / 4>(r + (size_t)row * C_REL, lane, tR, rp0, rp1, ra, rpt);
  row_stats<4, C_ENT / 4>(o + (size_t)row * C_ENT, lane, tO, op0, op1, oa, opt);

  if (lane == 0) {
    float gt   = spt * rpt * opt;
    float top1 = sp0 * rp0 * op0;
    float c1 = sp0 * rp1 * op1;
    float c2 = sp1 * rp0 * op1;
    float c3 = sp1 * rp1 * op0;
    float second = fminf(c1, fminf(c2, c3));
    bool cond = (sa == tS) && (ra == tR) && (oa == tO);
    float pre = cond ? second : top1;
    atomicAdd(out, fmaxf(1.0f - gt + pre, 0.0f) * (1.0f / (float)B));
  }
}

// ---------------- launch ----------------

extern "C" void kernel_launch(void* const* d_in, const int* in_sizes, int n_in,
                              void* d_out, int out_size, void* d_ws, size_t ws_size,
                              hipStream_t stream) {
  const float* s  = (const float*)d_in[0];
  const float* r  = (const float*)d_in[1];
  const float* o  = (const float*)d_in[2];
  const int*   st = (const int*)d_in[3];
  const int*   rt = (const int*)d_in[4];
  const int*   ot = (const int*)d_in[5];
  float* out = (float*)d_out;

  const size_t statBytes = (size_t)3 * B * sizeof(float4);   // 1.5 MiB
  if (ws_size >= statBytes + sizeof(unsigned)) {
    float4*   stat4   = (float4*)d_ws;
    unsigned* counter = (unsigned*)((char*)d_ws + statBytes);
    hipMemsetAsync(counter, 0, sizeof(unsigned), stream);
    stats_finish_kernel<<<NUNITS / 4, 256, 0, stream>>>(s, r, o, st, rt, ot,
                                                        stat4, counter, out);
  } else {
    hipMemsetAsync(d_out, 0, sizeof(float), stream);
    rank_loss_kernel<<<B / 4, 256, 0, stream>>>(s, r, o, st, rt, ot, out);
  }
}